// Round 12
// baseline (247.125 us; speedup 1.0000x reference)
//
#include <hip/hip_runtime.h>
#include <math.h>

// Problem constants
#define NB 4
#define HB 256
#define WB 256
#define CB 8
#define NPIX (NB*HB*WB)   // 262144
#define W2B 129           // rfft bins along W
#define TWO_PI_F 6.283185307179586f

typedef float f32x4 __attribute__((ext_vector_type(4)));

__device__ __forceinline__ float gelu_f(float x){
    float z = 0.7978845608028654f*(x + 0.044715f*x*x*x);
    return x * __builtin_amdgcn_rcpf(1.0f + __expf(-2.0f*z));
}

__device__ __forceinline__ unsigned pack_bf16x2(float a, float b){
    unsigned ua = __float_as_uint(a), ub = __float_as_uint(b);
    ua = (ua + 0x7FFFu + ((ua >> 16) & 1u)) >> 16;
    ub = (ub + 0x7FFFu + ((ub >> 16) & 1u)) >> 16;
    return ua | (ub << 16);
}
__device__ __forceinline__ float2 unpack_bf16x2(unsigned v){
    return make_float2(__uint_as_float(v << 16), __uint_as_float(v & 0xFFFF0000u));
}

__device__ __forceinline__ void ldcp(float* dst, const float* __restrict__ src, int n, int t){
    for (int i = t; i < n; i += 256) dst[i] = src[i];
}

// ---- prep ---------------------------------------------------------------
// Grid: [0..128] spectral filter; [129..1152] gamma 1px/thr;
//       [1153..2176] delta 1px/thr.  (round-8 structure, best measured)
// mat layout (uint4 rows): mat[(pix>>6)*2048 + j*256 + (pix&63)*4 + c],
//   c=0..3, each uint = bf16x2{k=2c,k=2c+1} of row j
// fpack layout: fpack[w2*16384 + q*1024 + h*4 + c] = bf16x2{re,im}
__global__ __launch_bounds__(256) void prep_kernel(
    const float* __restrict__ kin,
    const float* gw1,const float* gb1,const float* gw2,const float* gb2,const float* gw3,const float* gb3,
    const float* dw1,const float* db1,const float* dw2,const float* db2,const float* dw3,const float* db3,
    const float* fw1,const float* fb1,const float* fw2,const float* fb2,const float* fw3,const float* fb3,
    const float* iw1,const float* ib1,const float* iw2,const float* ib2,const float* iw3,const float* ib3,
    unsigned* __restrict__ gmat, unsigned* __restrict__ dmat,
    unsigned* __restrict__ fpack)
{
    __shared__ __align__(16) float sw[2816];
    int t = threadIdx.x;
    int b = blockIdx.x;
    if (b >= 129){
        int gd = (b >= 1153);
        const float* w1 = gd ? dw1 : gw1;  const float* b1 = gd ? db1 : gb1;
        const float* w2 = gd ? dw2 : gw2;  const float* b2 = gd ? db2 : gb2;
        const float* w3 = gd ? dw3 : gw3;  const float* b3 = gd ? db3 : gb3;
        ldcp(sw+0,   w1,  32, t); ldcp(sw+32,  b1, 16, t);
        ldcp(sw+48,  w2, 256, t); ldcp(sw+304, b2, 16, t);
        ldcp(sw+320, w3,1024, t); ldcp(sw+1344,b3, 64, t);
        __syncthreads();
        unsigned* mat = gd ? dmat : gmat;
        int pix = (b - (gd ? 1153 : 129))*256 + t;
        float2 kv = ((const float2*)kin)[pix];
        size_t base = (size_t)(pix >> 6)*2048 + (size_t)(pix & 63)*4;
        float h1[16], h2[16];
#pragma unroll
        for (int o = 0; o < 16; ++o)
            h1[o] = gelu_f(kv.x*sw[o] + kv.y*sw[16+o] + sw[32+o]);
#pragma unroll
        for (int oc = 0; oc < 4; ++oc){
            f32x4 acc = *(const f32x4*)(sw + 304 + oc*4);
#pragma unroll
            for (int i = 0; i < 16; ++i)
                acc += h1[i] * *(const f32x4*)(sw + 48 + i*16 + oc*4);
            h2[oc*4+0] = gelu_f(acc.x); h2[oc*4+1] = gelu_f(acc.y);
            h2[oc*4+2] = gelu_f(acc.z); h2[oc*4+3] = gelu_f(acc.w);
        }
        const float s = 1.0f/64.0f;
#pragma unroll
        for (int j = 0; j < 8; ++j){
            f32x4 A0 = *(const f32x4*)(sw + 1344 + j*8);
            f32x4 A1 = *(const f32x4*)(sw + 1344 + j*8 + 4);
#pragma unroll
            for (int i = 0; i < 16; ++i){
                A0 += h2[i] * *(const f32x4*)(sw + 320 + i*64 + j*8);
                A1 += h2[i] * *(const f32x4*)(sw + 320 + i*64 + j*8 + 4);
            }
            uint4 o = { pack_bf16x2(A0.x*s,A0.y*s), pack_bf16x2(A0.z*s,A0.w*s),
                        pack_bf16x2(A1.x*s,A1.y*s), pack_bf16x2(A1.z*s,A1.w*s) };
            *(uint4*)(mat + base + (size_t)j*256) = o;
        }
    } else {
        ldcp(sw+0,   fw1,  32, t); ldcp(sw+32,  fb1, 16, t);
        ldcp(sw+48,  fw2, 256, t); ldcp(sw+304, fb2, 16, t);
        ldcp(sw+320, fw3,1024, t); ldcp(sw+1344,fb3, 64, t);
        ldcp(sw+1408+0,   iw1,  32, t); ldcp(sw+1408+32,  ib1, 16, t);
        ldcp(sw+1408+48,  iw2, 256, t); ldcp(sw+1408+304, ib2, 16, t);
        ldcp(sw+1408+320, iw3,1024, t); ldcp(sw+1408+1344,ib3, 64, t);
        __syncthreads();
        int w2 = b;                                 // 0..128 (kx)
        float x = (float)w2;
        float y = (float)(t < 128 ? t : t - 256);   // ky signed, t = h-freq
        float h1r[16], h1i[16], h2r[16], h2i[16];
#pragma unroll
        for (int o = 0; o < 16; ++o){
            h1r[o] = gelu_f(x*sw[o] + y*sw[16+o] + sw[32+o]);
            h1i[o] = gelu_f(x*sw[1408+o] + y*sw[1408+16+o] + sw[1408+32+o]);
        }
#pragma unroll
        for (int o = 0; o < 16; ++o){
            float ar = sw[304+o], ai = sw[1408+304+o];
#pragma unroll
            for (int i = 0; i < 16; ++i){
                ar += h1r[i]*sw[48+i*16+o];
                ai += h1i[i]*sw[1408+48+i*16+o];
            }
            h2r[o] = gelu_f(ar); h2i[o] = gelu_f(ai);
        }
        const float s = 1.0f/64.0f;
#pragma unroll
        for (int q = 0; q < 16; ++q){
            f32x4 aR = *(const f32x4*)(sw + 1344 + q*4);
            f32x4 aI = *(const f32x4*)(sw + 1408 + 1344 + q*4);
#pragma unroll
            for (int i = 0; i < 16; ++i){
                aR += h2r[i] * *(const f32x4*)(sw + 320 + i*64 + q*4);
                aI += h2i[i] * *(const f32x4*)(sw + 1408 + 320 + i*64 + q*4);
            }
            uint4 out = { pack_bf16x2(aR.x*s, aI.x*s), pack_bf16x2(aR.y*s, aI.y*s),
                          pack_bf16x2(aR.z*s, aI.z*s), pack_bf16x2(aR.w*s, aI.w*s) };
            *(uint4*)(fpack + (size_t)w2*16384 + (size_t)q*1024 + (size_t)t*4) = out;
        }
    }
}

// ---- 256-pt complex FFT, 4 interleaved channels (f32x4 LDS) ------------
__device__ __forceinline__ void fft256v(f32x4* xr, f32x4* xi, int t, float sgn)
{
    int n2 = t >> 4, k1 = t & 15;
    float csA, snA; __sincosf(sgn*TWO_PI_F*(float)k1*(1.0f/16.0f), &snA, &csA);
    f32x4 ar = {0.f,0.f,0.f,0.f}, ai = {0.f,0.f,0.f,0.f};
    float cw = 1.f, sw = 0.f;
#pragma unroll
    for (int n1 = 0; n1 < 16; ++n1){
        f32x4 vr = xr[16*n1 + n2], vi = xi[16*n1 + n2];
        ar += vr*cw - vi*sw;
        ai += vr*sw + vi*cw;
        float cn = cw*csA - sw*snA;
        sw = cw*snA + sw*csA; cw = cn;
    }
    float cs2, sn2; __sincosf(sgn*TWO_PI_F*(float)(n2*k1)*(1.0f/256.0f), &sn2, &cs2);
    f32x4 br = ar*cs2 - ai*sn2;
    f32x4 bi = ar*sn2 + ai*cs2;
    __syncthreads();
    xr[t] = br; xi[t] = bi;
    __syncthreads();
    int k1b = t & 15, k2 = t >> 4;
    float csB, snB; __sincosf(sgn*TWO_PI_F*(float)k2*(1.0f/16.0f), &snB, &csB);
    f32x4 yr = {0.f,0.f,0.f,0.f}, yi = {0.f,0.f,0.f,0.f};
    cw = 1.f; sw = 0.f;
#pragma unroll
    for (int n2b = 0; n2b < 16; ++n2b){
        f32x4 br2 = xr[n2b*16 + k1b], bi2 = xi[n2b*16 + k1b];
        yr += br2*cw - bi2*sw;
        yi += br2*sw + bi2*cw;
        float cn = cw*csB - sw*snB;
        sw = cw*snB + sw*csB; cw = cn;
    }
    __syncthreads();
    xr[t] = yr; xi[t] = yi;
    __syncthreads();
}

// Core version: result returned in registers; no final store/sync.
__device__ __forceinline__ void fft256v_core(f32x4* xr, f32x4* xi, int t, float sgn,
                                             f32x4& outR, f32x4& outI)
{
    int n2 = t >> 4, k1 = t & 15;
    float csA, snA; __sincosf(sgn*TWO_PI_F*(float)k1*(1.0f/16.0f), &snA, &csA);
    f32x4 ar = {0.f,0.f,0.f,0.f}, ai = {0.f,0.f,0.f,0.f};
    float cw = 1.f, sw = 0.f;
#pragma unroll
    for (int n1 = 0; n1 < 16; ++n1){
        f32x4 vr = xr[16*n1 + n2], vi = xi[16*n1 + n2];
        ar += vr*cw - vi*sw;
        ai += vr*sw + vi*cw;
        float cn = cw*csA - sw*snA;
        sw = cw*snA + sw*csA; cw = cn;
    }
    float cs2, sn2; __sincosf(sgn*TWO_PI_F*(float)(n2*k1)*(1.0f/256.0f), &sn2, &cs2);
    f32x4 br = ar*cs2 - ai*sn2;
    f32x4 bi = ar*sn2 + ai*cs2;
    __syncthreads();
    xr[t] = br; xi[t] = bi;
    __syncthreads();
    int k1b = t & 15, k2 = t >> 4;
    float csB, snB; __sincosf(sgn*TWO_PI_F*(float)k2*(1.0f/16.0f), &snB, &csB);
    f32x4 yr = {0.f,0.f,0.f,0.f}, yi = {0.f,0.f,0.f,0.f};
    cw = 1.f; sw = 0.f;
#pragma unroll
    for (int n2b = 0; n2b < 16; ++n2b){
        f32x4 br2 = xr[n2b*16 + k1b], bi2 = xi[n2b*16 + k1b];
        yr += br2*cw - bi2*sw;
        yi += br2*sw + bi2*cw;
        float cn = cw*csB - sw*snB;
        sw = cw*snB + sw*csB; cw = cn;
    }
    outR = yr; outI = yi;
}

// du row -> fwd FFT -> Hermitian split -> spec write (t<=128)
__device__ __forceinline__ void fwd_store(
    f32x4* XR, f32x4* XI, const float* dv, int t, int n, int h,
    float2* __restrict__ spec)
{
    XR[t] = (f32x4){dv[0],dv[2],dv[4],dv[6]};
    XI[t] = (f32x4){dv[1],dv[3],dv[5],dv[7]};
    __syncthreads();
    fft256v(XR, XI, t, -1.f);
    if (t <= 128){
        int m = (256 - t) & 255;
        f32x4 zr = XR[t], zi = XI[t], yr = XR[m], yi = XI[m];
        float4* dst = (float4*)(spec + (((size_t)n*129 + t)*256 + h)*8);
        dst[0] = make_float4(0.5f*(zr.x+yr.x), 0.5f*(zi.x-yi.x), 0.5f*(zi.x+yi.x), 0.5f*(yr.x-zr.x));
        dst[1] = make_float4(0.5f*(zr.y+yr.y), 0.5f*(zi.y-yi.y), 0.5f*(zi.y+yi.y), 0.5f*(yr.y-zr.y));
        dst[2] = make_float4(0.5f*(zr.z+yr.z), 0.5f*(zi.z-yi.z), 0.5f*(zi.z+yi.z), 0.5f*(yr.z-zr.z));
        dst[3] = make_float4(0.5f*(zr.w+yr.w), 0.5f*(zi.w-yi.w), 0.5f*(zi.w+yi.w), 0.5f*(yr.w-zr.w));
    }
}

// Hermitian read (in regs, done by caller) -> inv FFT core -> gu[8]
__device__ __forceinline__ void inv_fft_from_quads(
    const float4& q0, const float4& q1, const float4& q2, const float4& q3,
    f32x4* XR, f32x4* XI, int t, float* gu)
{
    f32x4 xr, xi;
    if (t <= 128){
        xr = (f32x4){q0.x - q0.w, q1.x - q1.w, q2.x - q2.w, q3.x - q3.w};
        xi = (f32x4){q0.y + q0.z, q1.y + q1.z, q2.y + q2.z, q3.y + q3.z};
    } else {
        xr = (f32x4){ q0.x + q0.w,  q1.x + q1.w,  q2.x + q2.w,  q3.x + q3.w};
        xi = (f32x4){-q0.y + q0.z, -q1.y + q1.z, -q2.y + q2.z, -q3.y + q3.z};
    }
    XR[t] = xr; XI[t] = xi;
    __syncthreads();
    f32x4 gr, gi;
    fft256v_core(XR, XI, t, +1.f, gr, gi);
    const float s = 1.0f/65536.0f;
    gu[0]=gr.x*s; gu[1]=gi.x*s; gu[2]=gr.y*s; gu[3]=gi.y*s;
    gu[4]=gr.z*s; gu[5]=gi.z*s; gu[6]=gr.w*s; gu[7]=gi.w*s;
}

// matvec accumulate from prefetched uint4 rows: acc[k] += v[j]*M[j][k]
__device__ __forceinline__ void matvec_acc_reg(const uint4* q, const float* v, float* acc)
{
#pragma unroll
    for (int j = 0; j < 8; ++j){
        float vj = v[j];
        float2 f0 = unpack_bf16x2(q[j].x), f1 = unpack_bf16x2(q[j].y);
        float2 f2 = unpack_bf16x2(q[j].z), f3 = unpack_bf16x2(q[j].w);
        acc[0] += vj*f0.x; acc[1] += vj*f0.y;
        acc[2] += vj*f1.x; acc[3] += vj*f1.y;
        acc[4] += vj*f2.x; acc[5] += vj*f2.y;
        acc[6] += vj*f3.x; acc[7] += vj*f3.y;
    }
}
__device__ __forceinline__ void matvec_acc(const unsigned* __restrict__ mat,
                                           size_t base, const float* v, float* acc)
{
    const uint4* mp = (const uint4*)(mat + base);
    uint4 q[8];
#pragma unroll
    for (int j = 0; j < 8; ++j) q[j] = mp[j*64];
    matvec_acc_reg(q, v, acc);
}

// ---- initial: du = u*Delta, forward rfft along W -----------------------
__global__ __launch_bounds__(256) void fft_fwd_kernel(
    const float* __restrict__ u, const unsigned* __restrict__ dmat,
    float2* __restrict__ spec)
{
    __shared__ f32x4 XR[256], XI[256];
    int t = threadIdx.x, bid = blockIdx.x;
    int n = bid >> 8, h = bid & 255;
    const float* up = u + (size_t)bid*2048 + (size_t)t*8;
    float4 ua = ((const float4*)up)[0], ub = ((const float4*)up)[1];
    float uv[8] = {ua.x,ua.y,ua.z,ua.w, ub.x,ub.y,ub.z,ub.w};
    size_t base = (size_t)(bid*4 + (t>>6))*2048 + (size_t)(t&63)*4;
    float dv[8] = {0,0,0,0,0,0,0,0};
    matvec_acc(dmat, base, uv, dv);
    fwd_store(XR, XI, dv, t, n, h, spec);
}

// ---- fused: cfft along H -> per-frequency 8x8 complex mat -> icfft -----
__global__ __launch_bounds__(512) void ffth_mult_kernel(
    float2* __restrict__ spec, const unsigned* __restrict__ fpack)
{
    __shared__ f32x4 XR[2][256], XI[2][256];
    int tid = threadIdx.x;
    int t = tid & 255, g = tid >> 8;
    int n = blockIdx.x / 129, w2 = blockIdx.x % 129;
    float2* base = spec + ((size_t)(n*129 + w2))*2048;

    // prefetch filter quads BEFORE the first barrier (fence blocks hoisting)
    uint4 fq[8];
    {
        const uint4* fp = (const uint4*)(fpack + (size_t)w2*16384 + (size_t)t*4);
#pragma unroll
        for (int j = 0; j < 8; ++j) fq[j] = fp[(j*2 + g)*256];
    }

    const float4* rp = (const float4*)(base + (size_t)t*8);
    float4 ra = rp[g*2], rb = rp[g*2+1];
    XR[g][t] = (f32x4){ra.x, ra.z, rb.x, rb.z};
    XI[g][t] = (f32x4){ra.y, ra.w, rb.y, rb.w};
    __syncthreads();
    f32x4 sR, sI;
    fft256v_core(XR[g], XI[g], t, -1.f, sR, sI);
    __syncthreads();
    XR[g][t] = sR; XI[g][t] = sI;
    __syncthreads();
    f32x4 oR = XR[1-g][t], oI = XI[1-g][t];
    f32x4 aR = g ? oR : sR, aI = g ? oI : sI;       // ch 0-3
    f32x4 bR = g ? sR : oR, bI = g ? sI : oI;       // ch 4-7
    float sr[8] = {aR.x,aR.y,aR.z,aR.w, bR.x,bR.y,bR.z,bR.w};
    float si[8] = {aI.x,aI.y,aI.z,aI.w, bI.x,bI.y,bI.z,bI.w};
    f32x4 orr = {0.f,0.f,0.f,0.f}, oii = {0.f,0.f,0.f,0.f};
#pragma unroll
    for (int j = 0; j < 8; ++j){
        float sjr = sr[j], sji = si[j];
        float2 f0 = unpack_bf16x2(fq[j].x), f1 = unpack_bf16x2(fq[j].y);
        float2 f2 = unpack_bf16x2(fq[j].z), f3 = unpack_bf16x2(fq[j].w);
        orr.x += sjr*f0.x - sji*f0.y;  oii.x += sjr*f0.y + sji*f0.x;
        orr.y += sjr*f1.x - sji*f1.y;  oii.y += sjr*f1.y + sji*f1.x;
        orr.z += sjr*f2.x - sji*f2.y;  oii.z += sjr*f2.y + sji*f2.x;
        orr.w += sjr*f3.x - sji*f3.y;  oii.w += sjr*f3.y + sji*f3.x;
    }
    __syncthreads();
    XR[g][t] = orr; XI[g][t] = oii;
    __syncthreads();
    f32x4 vR, vI;
    fft256v_core(XR[g], XI[g], t, +1.f, vR, vI);
    float4* wp = (float4*)(base + (size_t)t*8);
    wp[g*2]   = make_float4(vR.x, vI.x, vR.y, vI.y);
    wp[g*2+1] = make_float4(vR.z, vI.z, vR.w, vI.w);
}

// ---- fused step: inv-W-FFT -> u' = 2u+(gu-u)G -> du = u'D -> fwd-W-FFT -
__global__ __launch_bounds__(256) void born_step_kernel(
    float2* __restrict__ spec, const float* __restrict__ u_in,
    float* __restrict__ u_out, const unsigned* __restrict__ gmat,
    const unsigned* __restrict__ dmat)
{
    __shared__ f32x4 XR[256], XI[256];
    int t = threadIdx.x, bid = blockIdx.x;
    int n = bid >> 8, h = bid & 255;

    // prefetch spec row + u row + gmat rows BEFORE the first barrier
    int w2 = (t <= 128) ? t : 256 - t;
    const float4* rp = (const float4*)(spec + (((size_t)n*129 + w2)*256 + h)*8);
    float4 q0 = rp[0], q1 = rp[1], q2 = rp[2], q3 = rp[3];
    const float* up = u_in + (size_t)bid*2048 + (size_t)t*8;
    float4 ua = ((const float4*)up)[0], ub = ((const float4*)up)[1];
    size_t base = (size_t)(bid*4 + (t>>6))*2048 + (size_t)(t&63)*4;
    uint4 gq[8];
    {
        const uint4* gp = (const uint4*)(gmat + base);
#pragma unroll
        for (int j = 0; j < 8; ++j) gq[j] = gp[j*64];
    }

    float gu[8];
    inv_fft_from_quads(q0, q1, q2, q3, XR, XI, t, gu);

    float uv[8] = {ua.x,ua.y,ua.z,ua.w, ub.x,ub.y,ub.z,ub.w};
    float e[8], acc[8];
#pragma unroll
    for (int c = 0; c < 8; ++c){ e[c] = gu[c] - uv[c]; acc[c] = 2.0f*uv[c]; }
    matvec_acc_reg(gq, e, acc);
    float* op = u_out + (size_t)bid*2048 + (size_t)t*8;
    ((float4*)op)[0] = make_float4(acc[0],acc[1],acc[2],acc[3]);
    ((float4*)op)[1] = make_float4(acc[4],acc[5],acc[6],acc[7]);

    float dv[8] = {0,0,0,0,0,0,0,0};
    matvec_acc(dmat, base, acc, dv);
    __syncthreads();   // guard: laggards may still read XR/XI from inv stage-2
    fwd_store(XR, XI, dv, t, n, h, spec);
}

// ---- final: inv-W-FFT -> u' -> gelu(u'+bias) -> out --------------------
__global__ __launch_bounds__(256) void final_kernel(
    const float2* __restrict__ spec, const float* __restrict__ u_in,
    const unsigned* __restrict__ gmat, const float* __restrict__ bias,
    float* __restrict__ out)
{
    __shared__ f32x4 XR[256], XI[256];
    int t = threadIdx.x, bid = blockIdx.x;
    int n = bid >> 8, h = bid & 255;

    int w2 = (t <= 128) ? t : 256 - t;
    const float4* rp = (const float4*)(spec + (((size_t)n*129 + w2)*256 + h)*8);
    float4 q0 = rp[0], q1 = rp[1], q2 = rp[2], q3 = rp[3];
    const float* up = u_in + (size_t)bid*2048 + (size_t)t*8;
    float4 ua = ((const float4*)up)[0], ub = ((const float4*)up)[1];
    size_t base = (size_t)(bid*4 + (t>>6))*2048 + (size_t)(t&63)*4;
    uint4 gq[8];
    {
        const uint4* gp = (const uint4*)(gmat + base);
#pragma unroll
        for (int j = 0; j < 8; ++j) gq[j] = gp[j*64];
    }

    float gu[8];
    inv_fft_from_quads(q0, q1, q2, q3, XR, XI, t, gu);

    float uv[8] = {ua.x,ua.y,ua.z,ua.w, ub.x,ub.y,ub.z,ub.w};
    float e[8], acc[8];
#pragma unroll
    for (int c = 0; c < 8; ++c){ e[c] = gu[c] - uv[c]; acc[c] = 2.0f*uv[c]; }
    matvec_acc_reg(gq, e, acc);
#pragma unroll
    for (int k = 0; k < 8; ++k) acc[k] = gelu_f(acc[k] + bias[k]);
    float* op = out + (size_t)bid*2048 + (size_t)t*8;
    ((float4*)op)[0] = make_float4(acc[0],acc[1],acc[2],acc[3]);
    ((float4*)op)[1] = make_float4(acc[4],acc[5],acc[6],acc[7]);
}

extern "C" void kernel_launch(void* const* d_in, const int* in_sizes, int n_in,
                              void* d_out, int out_size, void* d_ws, size_t ws_size,
                              hipStream_t stream) {
    const float* u_in = (const float*)d_in[0];
    const float* k_in = (const float*)d_in[1];
    const float* Wp[24];
    for (int i = 0; i < 24; ++i) Wp[i] = (const float*)d_in[2+i];
    const float* bias = (const float*)d_in[26];

    char* base = (char*)d_ws;
    unsigned* gmat  = (unsigned*)(base);                  // 32 MiB (bf16 pairs)
    unsigned* dmat  = (unsigned*)(base + 33554432ull);    // 32 MiB
    unsigned* fpack = (unsigned*)(base + 67108864ull);    // 8.45 MB (bf16 pairs)
    float*    u_ws  = (float*)   (base + 75563008ull);    // 8 MiB
    float2*   spec  = (float2*)  (base + 83951616ull);    // 8.45 MB -> ~92 MB

    prep_kernel<<<2177, 256, 0, stream>>>(k_in,
        Wp[0],Wp[1],Wp[2],Wp[3],Wp[4],Wp[5],
        Wp[6],Wp[7],Wp[8],Wp[9],Wp[10],Wp[11],
        Wp[12],Wp[13],Wp[14],Wp[15],Wp[16],Wp[17],
        Wp[18],Wp[19],Wp[20],Wp[21],Wp[22],Wp[23],
        gmat, dmat, fpack);

    fft_fwd_kernel<<<1024, 256, 0, stream>>>(u_in, dmat, spec);
    for (int it = 0; it < 4; ++it){
        ffth_mult_kernel<<<516, 512, 0, stream>>>(spec, fpack);
        if (it < 3){
            born_step_kernel<<<1024, 256, 0, stream>>>(
                spec, (it == 0) ? u_in : u_ws, u_ws, gmat, dmat);
        } else {
            final_kernel<<<1024, 256, 0, stream>>>(spec, u_ws, gmat, bias, (float*)d_out);
        }
    }
}

// Round 13
// 211.000 us; speedup vs baseline: 1.1712x; 1.1712x over previous
//
#include <hip/hip_runtime.h>
#include <math.h>

// Problem constants
#define NB 4
#define HB 256
#define WB 256
#define CB 8
#define NPIX (NB*HB*WB)   // 262144
#define W2B 129           // rfft bins along W
#define TWO_PI_F 6.283185307179586f

typedef float f32x4 __attribute__((ext_vector_type(4)));

__device__ __forceinline__ float gelu_f(float x){
    float z = 0.7978845608028654f*(x + 0.044715f*x*x*x);
    return x * __builtin_amdgcn_rcpf(1.0f + __expf(-2.0f*z));
}

__device__ __forceinline__ unsigned pack_bf16x2(float a, float b){
    unsigned ua = __float_as_uint(a), ub = __float_as_uint(b);
    ua = (ua + 0x7FFFu + ((ua >> 16) & 1u)) >> 16;
    ub = (ub + 0x7FFFu + ((ub >> 16) & 1u)) >> 16;
    return ua | (ub << 16);
}
__device__ __forceinline__ float2 unpack_bf16x2(unsigned v){
    return make_float2(__uint_as_float(v << 16), __uint_as_float(v & 0xFFFF0000u));
}

__device__ __forceinline__ void ldcp(float* dst, const float* __restrict__ src, int n, int t){
    for (int i = t; i < n; i += 256) dst[i] = src[i];
}

// ---- prep (round-10 version, best measured) ----------------------------
// Grid: [0..128] spectral filter; [129..640] gamma 2px/thr; [641..1152] delta.
// mat layout (uint4 rows): mat[(pix>>6)*2048 + j*256 + (pix&63)*4 + c]
// fpack layout: fpack[w2*16384 + q*1024 + h*4 + c] = bf16x2{re,im}
__global__ __launch_bounds__(256) void prep_kernel(
    const float* __restrict__ kin,
    const float* gw1,const float* gb1,const float* gw2,const float* gb2,const float* gw3,const float* gb3,
    const float* dw1,const float* db1,const float* dw2,const float* db2,const float* dw3,const float* db3,
    const float* fw1,const float* fb1,const float* fw2,const float* fb2,const float* fw3,const float* fb3,
    const float* iw1,const float* ib1,const float* iw2,const float* ib2,const float* iw3,const float* ib3,
    unsigned* __restrict__ gmat, unsigned* __restrict__ dmat,
    unsigned* __restrict__ fpack)
{
    __shared__ __align__(16) float sw[2816];
    int t = threadIdx.x;
    int b = blockIdx.x;
    if (b >= 129){
        int gd = (b >= 641);
        const float* w1 = gd ? dw1 : gw1;  const float* b1 = gd ? db1 : gb1;
        const float* w2 = gd ? dw2 : gw2;  const float* b2 = gd ? db2 : gb2;
        const float* w3 = gd ? dw3 : gw3;  const float* b3 = gd ? db3 : gb3;
        ldcp(sw+0,   w1,  32, t); ldcp(sw+32,  b1, 16, t);
        ldcp(sw+48,  w2, 256, t); ldcp(sw+304, b2, 16, t);
        ldcp(sw+320, w3,1024, t); ldcp(sw+1344,b3, 64, t);
        __syncthreads();
        unsigned* mat = gd ? dmat : gmat;
        int p0 = (b - (gd ? 641 : 129))*512 + t;
        int p1 = p0 + 256;
        float2 kv0 = ((const float2*)kin)[p0];
        float2 kv1 = ((const float2*)kin)[p1];
        size_t base0 = (size_t)(p0 >> 6)*2048 + (size_t)(p0 & 63)*4;
        size_t base1 = (size_t)(p1 >> 6)*2048 + (size_t)(p1 & 63)*4;
        float h1[2][16], h2[2][16];
#pragma unroll
        for (int o = 0; o < 16; ++o){
            float wx = sw[o], wy = sw[16+o], bo = sw[32+o];
            h1[0][o] = gelu_f(kv0.x*wx + kv0.y*wy + bo);
            h1[1][o] = gelu_f(kv1.x*wx + kv1.y*wy + bo);
        }
#pragma unroll
        for (int oc = 0; oc < 4; ++oc){
            f32x4 bb = *(const f32x4*)(sw + 304 + oc*4);
            f32x4 a0 = bb, a1 = bb;
#pragma unroll
            for (int i = 0; i < 16; ++i){
                f32x4 w = *(const f32x4*)(sw + 48 + i*16 + oc*4);
                a0 += h1[0][i]*w; a1 += h1[1][i]*w;
            }
            h2[0][oc*4+0]=gelu_f(a0.x); h2[0][oc*4+1]=gelu_f(a0.y);
            h2[0][oc*4+2]=gelu_f(a0.z); h2[0][oc*4+3]=gelu_f(a0.w);
            h2[1][oc*4+0]=gelu_f(a1.x); h2[1][oc*4+1]=gelu_f(a1.y);
            h2[1][oc*4+2]=gelu_f(a1.z); h2[1][oc*4+3]=gelu_f(a1.w);
        }
        const float s = 1.0f/64.0f;
#pragma unroll
        for (int j = 0; j < 8; ++j){
            f32x4 bA = *(const f32x4*)(sw + 1344 + j*8);
            f32x4 bB = *(const f32x4*)(sw + 1344 + j*8 + 4);
            f32x4 A0 = bA, A1 = bB, B0 = bA, B1 = bB;
#pragma unroll
            for (int i = 0; i < 16; ++i){
                f32x4 wA = *(const f32x4*)(sw + 320 + i*64 + j*8);
                f32x4 wB = *(const f32x4*)(sw + 320 + i*64 + j*8 + 4);
                float h0 = h2[0][i], h1v = h2[1][i];
                A0 += h0*wA; A1 += h0*wB;
                B0 += h1v*wA; B1 += h1v*wB;
            }
            uint4 o0 = { pack_bf16x2(A0.x*s,A0.y*s), pack_bf16x2(A0.z*s,A0.w*s),
                         pack_bf16x2(A1.x*s,A1.y*s), pack_bf16x2(A1.z*s,A1.w*s) };
            uint4 o1 = { pack_bf16x2(B0.x*s,B0.y*s), pack_bf16x2(B0.z*s,B0.w*s),
                         pack_bf16x2(B1.x*s,B1.y*s), pack_bf16x2(B1.z*s,B1.w*s) };
            *(uint4*)(mat + base0 + (size_t)j*256) = o0;
            *(uint4*)(mat + base1 + (size_t)j*256) = o1;
        }
    } else {
        ldcp(sw+0,   fw1,  32, t); ldcp(sw+32,  fb1, 16, t);
        ldcp(sw+48,  fw2, 256, t); ldcp(sw+304, fb2, 16, t);
        ldcp(sw+320, fw3,1024, t); ldcp(sw+1344,fb3, 64, t);
        ldcp(sw+1408+0,   iw1,  32, t); ldcp(sw+1408+32,  ib1, 16, t);
        ldcp(sw+1408+48,  iw2, 256, t); ldcp(sw+1408+304, ib2, 16, t);
        ldcp(sw+1408+320, iw3,1024, t); ldcp(sw+1408+1344,ib3, 64, t);
        __syncthreads();
        int w2 = b;                                 // 0..128 (kx)
        float x = (float)w2;
        float y = (float)(t < 128 ? t : t - 256);   // ky signed, t = h-freq
        float h1r[16], h1i[16], h2r[16], h2i[16];
#pragma unroll
        for (int o = 0; o < 16; ++o){
            h1r[o] = gelu_f(x*sw[o] + y*sw[16+o] + sw[32+o]);
            h1i[o] = gelu_f(x*sw[1408+o] + y*sw[1408+16+o] + sw[1408+32+o]);
        }
#pragma unroll
        for (int o = 0; o < 16; ++o){
            float ar = sw[304+o], ai = sw[1408+304+o];
#pragma unroll
            for (int i = 0; i < 16; ++i){
                ar += h1r[i]*sw[48+i*16+o];
                ai += h1i[i]*sw[1408+48+i*16+o];
            }
            h2r[o] = gelu_f(ar); h2i[o] = gelu_f(ai);
        }
        const float s = 1.0f/64.0f;
#pragma unroll
        for (int q = 0; q < 16; ++q){
            f32x4 aR = *(const f32x4*)(sw + 1344 + q*4);
            f32x4 aI = *(const f32x4*)(sw + 1408 + 1344 + q*4);
#pragma unroll
            for (int i = 0; i < 16; ++i){
                aR += h2r[i] * *(const f32x4*)(sw + 320 + i*64 + q*4);
                aI += h2i[i] * *(const f32x4*)(sw + 1408 + 320 + i*64 + q*4);
            }
            uint4 out = { pack_bf16x2(aR.x*s, aI.x*s), pack_bf16x2(aR.y*s, aI.y*s),
                          pack_bf16x2(aR.z*s, aI.z*s), pack_bf16x2(aR.w*s, aI.w*s) };
            *(uint4*)(fpack + (size_t)w2*16384 + (size_t)q*1024 + (size_t)t*4) = out;
        }
    }
}

// ---- 256-pt complex FFT, 4 interleaved channels (f32x4 LDS) ------------
__device__ __forceinline__ void fft256v(f32x4* xr, f32x4* xi, int t, float sgn)
{
    int n2 = t >> 4, k1 = t & 15;
    float csA, snA; __sincosf(sgn*TWO_PI_F*(float)k1*(1.0f/16.0f), &snA, &csA);
    f32x4 ar = {0.f,0.f,0.f,0.f}, ai = {0.f,0.f,0.f,0.f};
    float cw = 1.f, sw = 0.f;
#pragma unroll
    for (int n1 = 0; n1 < 16; ++n1){
        f32x4 vr = xr[16*n1 + n2], vi = xi[16*n1 + n2];
        ar += vr*cw - vi*sw;
        ai += vr*sw + vi*cw;
        float cn = cw*csA - sw*snA;
        sw = cw*snA + sw*csA; cw = cn;
    }
    float cs2, sn2; __sincosf(sgn*TWO_PI_F*(float)(n2*k1)*(1.0f/256.0f), &sn2, &cs2);
    f32x4 br = ar*cs2 - ai*sn2;
    f32x4 bi = ar*sn2 + ai*cs2;
    __syncthreads();
    xr[t] = br; xi[t] = bi;
    __syncthreads();
    int k1b = t & 15, k2 = t >> 4;
    float csB, snB; __sincosf(sgn*TWO_PI_F*(float)k2*(1.0f/16.0f), &snB, &csB);
    f32x4 yr = {0.f,0.f,0.f,0.f}, yi = {0.f,0.f,0.f,0.f};
    cw = 1.f; sw = 0.f;
#pragma unroll
    for (int n2b = 0; n2b < 16; ++n2b){
        f32x4 br2 = xr[n2b*16 + k1b], bi2 = xi[n2b*16 + k1b];
        yr += br2*cw - bi2*sw;
        yi += br2*sw + bi2*cw;
        float cn = cw*csB - sw*snB;
        sw = cw*snB + sw*csB; cw = cn;
    }
    __syncthreads();
    xr[t] = yr; xi[t] = yi;
    __syncthreads();
}

// Core version: result returned in registers; no final store/sync.
__device__ __forceinline__ void fft256v_core(f32x4* xr, f32x4* xi, int t, float sgn,
                                             f32x4& outR, f32x4& outI)
{
    int n2 = t >> 4, k1 = t & 15;
    float csA, snA; __sincosf(sgn*TWO_PI_F*(float)k1*(1.0f/16.0f), &snA, &csA);
    f32x4 ar = {0.f,0.f,0.f,0.f}, ai = {0.f,0.f,0.f,0.f};
    float cw = 1.f, sw = 0.f;
#pragma unroll
    for (int n1 = 0; n1 < 16; ++n1){
        f32x4 vr = xr[16*n1 + n2], vi = xi[16*n1 + n2];
        ar += vr*cw - vi*sw;
        ai += vr*sw + vi*cw;
        float cn = cw*csA - sw*snA;
        sw = cw*snA + sw*csA; cw = cn;
    }
    float cs2, sn2; __sincosf(sgn*TWO_PI_F*(float)(n2*k1)*(1.0f/256.0f), &sn2, &cs2);
    f32x4 br = ar*cs2 - ai*sn2;
    f32x4 bi = ar*sn2 + ai*cs2;
    __syncthreads();
    xr[t] = br; xi[t] = bi;
    __syncthreads();
    int k1b = t & 15, k2 = t >> 4;
    float csB, snB; __sincosf(sgn*TWO_PI_F*(float)k2*(1.0f/16.0f), &snB, &csB);
    f32x4 yr = {0.f,0.f,0.f,0.f}, yi = {0.f,0.f,0.f,0.f};
    cw = 1.f; sw = 0.f;
#pragma unroll
    for (int n2b = 0; n2b < 16; ++n2b){
        f32x4 br2 = xr[n2b*16 + k1b], bi2 = xi[n2b*16 + k1b];
        yr += br2*cw - bi2*sw;
        yi += br2*sw + bi2*cw;
        float cn = cw*csB - sw*snB;
        sw = cw*snB + sw*csB; cw = cn;
    }
    outR = yr; outI = yi;
}

// 8-channel core: two f32x4 halves batched through one barrier set.
__device__ __forceinline__ void fft256v8_core(
    f32x4 (*xr)[256], f32x4 (*xi)[256], int t, float sgn,
    f32x4& o0R, f32x4& o0I, f32x4& o1R, f32x4& o1I)
{
    int n2 = t >> 4, k1 = t & 15;
    float csA, snA; __sincosf(sgn*TWO_PI_F*(float)k1*(1.0f/16.0f), &snA, &csA);
    f32x4 a0r={0.f,0.f,0.f,0.f}, a0i=a0r, a1r=a0r, a1i=a0r;
    float cw = 1.f, sw = 0.f;
#pragma unroll
    for (int n1 = 0; n1 < 16; ++n1){
        int idx = 16*n1 + n2;
        f32x4 v0r = xr[0][idx], v0i = xi[0][idx];
        f32x4 v1r = xr[1][idx], v1i = xi[1][idx];
        a0r += v0r*cw - v0i*sw;  a0i += v0r*sw + v0i*cw;
        a1r += v1r*cw - v1i*sw;  a1i += v1r*sw + v1i*cw;
        float cn = cw*csA - sw*snA;
        sw = cw*snA + sw*csA; cw = cn;
    }
    float cs2, sn2; __sincosf(sgn*TWO_PI_F*(float)(n2*k1)*(1.0f/256.0f), &sn2, &cs2);
    f32x4 b0r = a0r*cs2 - a0i*sn2, b0i = a0r*sn2 + a0i*cs2;
    f32x4 b1r = a1r*cs2 - a1i*sn2, b1i = a1r*sn2 + a1i*cs2;
    __syncthreads();
    xr[0][t]=b0r; xi[0][t]=b0i; xr[1][t]=b1r; xi[1][t]=b1i;
    __syncthreads();
    int k1b = t & 15, k2 = t >> 4;
    float csB, snB; __sincosf(sgn*TWO_PI_F*(float)k2*(1.0f/16.0f), &snB, &csB);
    f32x4 y0r={0.f,0.f,0.f,0.f}, y0i=y0r, y1r=y0r, y1i=y0r;
    cw = 1.f; sw = 0.f;
#pragma unroll
    for (int n2b = 0; n2b < 16; ++n2b){
        int idx = n2b*16 + k1b;
        f32x4 c0r = xr[0][idx], c0i = xi[0][idx];
        f32x4 c1r = xr[1][idx], c1i = xi[1][idx];
        y0r += c0r*cw - c0i*sw;  y0i += c0r*sw + c0i*cw;
        y1r += c1r*cw - c1i*sw;  y1i += c1r*sw + c1i*cw;
        float cn = cw*csB - sw*snB;
        sw = cw*snB + sw*csB; cw = cn;
    }
    o0R = y0r; o0I = y0i; o1R = y1r; o1I = y1i;
}

// du row -> fwd FFT -> Hermitian split -> spec write (t<=128)
__device__ __forceinline__ void fwd_store(
    f32x4* XR, f32x4* XI, const float* dv, int t, int n, int h,
    float2* __restrict__ spec)
{
    XR[t] = (f32x4){dv[0],dv[2],dv[4],dv[6]};
    XI[t] = (f32x4){dv[1],dv[3],dv[5],dv[7]};
    __syncthreads();
    fft256v(XR, XI, t, -1.f);
    if (t <= 128){
        int m = (256 - t) & 255;
        f32x4 zr = XR[t], zi = XI[t], yr = XR[m], yi = XI[m];
        float4* dst = (float4*)(spec + (((size_t)n*129 + t)*256 + h)*8);
        dst[0] = make_float4(0.5f*(zr.x+yr.x), 0.5f*(zi.x-yi.x), 0.5f*(zi.x+yi.x), 0.5f*(yr.x-zr.x));
        dst[1] = make_float4(0.5f*(zr.y+yr.y), 0.5f*(zi.y-yi.y), 0.5f*(zi.y+yi.y), 0.5f*(yr.y-zr.y));
        dst[2] = make_float4(0.5f*(zr.z+yr.z), 0.5f*(zi.z-yi.z), 0.5f*(zi.z+yi.z), 0.5f*(yr.z-zr.z));
        dst[3] = make_float4(0.5f*(zr.w+yr.w), 0.5f*(zi.w-yi.w), 0.5f*(zi.w+yi.w), 0.5f*(yr.w-zr.w));
    }
}

// direct Hermitian read -> inv FFT (core) -> gu[8] in registers.
__device__ __forceinline__ void inv_fft_to_gu(
    const float2* __restrict__ spec, f32x4* XR, f32x4* XI,
    int t, int n, int h, float* gu)
{
    int w2 = (t <= 128) ? t : 256 - t;
    const float4* rp = (const float4*)(spec + (((size_t)n*129 + w2)*256 + h)*8);
    float4 q0 = rp[0], q1 = rp[1], q2 = rp[2], q3 = rp[3];
    f32x4 xr, xi;
    if (t <= 128){
        xr = (f32x4){q0.x - q0.w, q1.x - q1.w, q2.x - q2.w, q3.x - q3.w};
        xi = (f32x4){q0.y + q0.z, q1.y + q1.z, q2.y + q2.z, q3.y + q3.z};
    } else {
        xr = (f32x4){ q0.x + q0.w,  q1.x + q1.w,  q2.x + q2.w,  q3.x + q3.w};
        xi = (f32x4){-q0.y + q0.z, -q1.y + q1.z, -q2.y + q2.z, -q3.y + q3.z};
    }
    XR[t] = xr; XI[t] = xi;
    __syncthreads();
    f32x4 gr, gi;
    fft256v_core(XR, XI, t, +1.f, gr, gi);
    const float s = 1.0f/65536.0f;
    gu[0]=gr.x*s; gu[1]=gi.x*s; gu[2]=gr.y*s; gu[3]=gi.y*s;
    gu[4]=gr.z*s; gu[5]=gi.z*s; gu[6]=gr.w*s; gu[7]=gi.w*s;
}

// matvec accumulate: acc[k] += v[j] * M[j][k], M in uint4-row layout
__device__ __forceinline__ void matvec_acc(const unsigned* __restrict__ mat,
                                           size_t base, const float* v, float* acc)
{
    const uint4* mp = (const uint4*)(mat + base);
#pragma unroll
    for (int j = 0; j < 8; ++j){
        uint4 q = mp[j*64];
        float vj = v[j];
        float2 f0 = unpack_bf16x2(q.x), f1 = unpack_bf16x2(q.y);
        float2 f2 = unpack_bf16x2(q.z), f3 = unpack_bf16x2(q.w);
        acc[0] += vj*f0.x; acc[1] += vj*f0.y;
        acc[2] += vj*f1.x; acc[3] += vj*f1.y;
        acc[4] += vj*f2.x; acc[5] += vj*f2.y;
        acc[6] += vj*f3.x; acc[7] += vj*f3.y;
    }
}

// ---- initial: du = u*Delta, forward rfft along W -----------------------
__global__ __launch_bounds__(256) void fft_fwd_kernel(
    const float* __restrict__ u, const unsigned* __restrict__ dmat,
    float2* __restrict__ spec)
{
    __shared__ f32x4 XR[256], XI[256];
    int t = threadIdx.x, bid = blockIdx.x;
    int n = bid >> 8, h = bid & 255;
    const float* up = u + (size_t)bid*2048 + (size_t)t*8;
    float4 ua = ((const float4*)up)[0], ub = ((const float4*)up)[1];
    float uv[8] = {ua.x,ua.y,ua.z,ua.w, ub.x,ub.y,ub.z,ub.w};
    size_t base = (size_t)(bid*4 + (t>>6))*2048 + (size_t)(t&63)*4;
    float dv[8] = {0,0,0,0,0,0,0,0};
    matvec_acc(dmat, base, uv, dv);
    fwd_store(XR, XI, dv, t, n, h, spec);
}

// ---- fused: cfft along H -> per-frequency 8x8 complex mat -> icfft -----
// 256 threads, all 8 channels per thread (batched FFT, thread-local matmul).
__global__ __launch_bounds__(256) void ffth_mult_kernel(
    float2* __restrict__ spec, const unsigned* __restrict__ fpack)
{
    __shared__ f32x4 XR[2][256], XI[2][256];
    int t = threadIdx.x;
    int n = blockIdx.x / 129, w2 = blockIdx.x % 129;
    float2* base = spec + ((size_t)(n*129 + w2))*2048;
    const float4* rp = (const float4*)(base + (size_t)t*8);
    float4 r0 = rp[0], r1 = rp[1], r2 = rp[2], r3 = rp[3];
    XR[0][t] = (f32x4){r0.x, r0.z, r1.x, r1.z};
    XI[0][t] = (f32x4){r0.y, r0.w, r1.y, r1.w};
    XR[1][t] = (f32x4){r2.x, r2.z, r3.x, r3.z};
    XI[1][t] = (f32x4){r2.y, r2.w, r3.y, r3.w};
    __syncthreads();
    f32x4 s0R, s0I, s1R, s1I;
    fft256v8_core(XR, XI, t, -1.f, s0R, s0I, s1R, s1I);

    // thread-local 8x8 complex matmul (no cross-group handoff)
    float sr[8] = {s0R.x,s0R.y,s0R.z,s0R.w, s1R.x,s1R.y,s1R.z,s1R.w};
    float si[8] = {s0I.x,s0I.y,s0I.z,s0I.w, s1I.x,s1I.y,s1I.z,s1I.w};
    f32x4 o0R={0.f,0.f,0.f,0.f}, o0I=o0R, o1R=o0R, o1I=o0R;
    const uint4* fp = (const uint4*)(fpack + (size_t)w2*16384 + (size_t)t*4);
#pragma unroll
    for (int j = 0; j < 8; ++j){
        float sjr = sr[j], sji = si[j];
        uint4 fa = fp[(j*2+0)*256];       // out k 0..3
        uint4 fb = fp[(j*2+1)*256];       // out k 4..7
        float2 f0 = unpack_bf16x2(fa.x), f1 = unpack_bf16x2(fa.y);
        float2 f2 = unpack_bf16x2(fa.z), f3 = unpack_bf16x2(fa.w);
        o0R.x += sjr*f0.x - sji*f0.y;  o0I.x += sjr*f0.y + sji*f0.x;
        o0R.y += sjr*f1.x - sji*f1.y;  o0I.y += sjr*f1.y + sji*f1.x;
        o0R.z += sjr*f2.x - sji*f2.y;  o0I.z += sjr*f2.y + sji*f2.x;
        o0R.w += sjr*f3.x - sji*f3.y;  o0I.w += sjr*f3.y + sji*f3.x;
        float2 g0 = unpack_bf16x2(fb.x), g1 = unpack_bf16x2(fb.y);
        float2 g2 = unpack_bf16x2(fb.z), g3 = unpack_bf16x2(fb.w);
        o1R.x += sjr*g0.x - sji*g0.y;  o1I.x += sjr*g0.y + sji*g0.x;
        o1R.y += sjr*g1.x - sji*g1.y;  o1I.y += sjr*g1.y + sji*g1.x;
        o1R.z += sjr*g2.x - sji*g2.y;  o1I.z += sjr*g2.y + sji*g2.x;
        o1R.w += sjr*g3.x - sji*g3.y;  o1I.w += sjr*g3.y + sji*g3.x;
    }
    __syncthreads();    // fwd stage-2 LDS reads complete
    XR[0][t]=o0R; XI[0][t]=o0I; XR[1][t]=o1R; XI[1][t]=o1I;
    __syncthreads();
    f32x4 v0R, v0I, v1R, v1I;
    fft256v8_core(XR, XI, t, +1.f, v0R, v0I, v1R, v1I);
    float4* wp = (float4*)(base + (size_t)t*8);
    wp[0] = make_float4(v0R.x, v0I.x, v0R.y, v0I.y);
    wp[1] = make_float4(v0R.z, v0I.z, v0R.w, v0I.w);
    wp[2] = make_float4(v1R.x, v1I.x, v1R.y, v1I.y);
    wp[3] = make_float4(v1R.z, v1I.z, v1R.w, v1I.w);
}

// ---- fused step: inv-W-FFT -> u' = 2u+(gu-u)G -> du = u'D -> fwd-W-FFT -
__global__ __launch_bounds__(256) void born_step_kernel(
    float2* __restrict__ spec, const float* __restrict__ u_in,
    float* __restrict__ u_out, const unsigned* __restrict__ gmat,
    const unsigned* __restrict__ dmat)
{
    __shared__ f32x4 XR[256], XI[256];
    int t = threadIdx.x, bid = blockIdx.x;
    int n = bid >> 8, h = bid & 255;
    float gu[8];
    inv_fft_to_gu(spec, XR, XI, t, n, h, gu);

    const float* up = u_in + (size_t)bid*2048 + (size_t)t*8;
    float4 ua = ((const float4*)up)[0], ub = ((const float4*)up)[1];
    float uv[8] = {ua.x,ua.y,ua.z,ua.w, ub.x,ub.y,ub.z,ub.w};
    float e[8], acc[8];
#pragma unroll
    for (int c = 0; c < 8; ++c){ e[c] = gu[c] - uv[c]; acc[c] = 2.0f*uv[c]; }
    size_t base = (size_t)(bid*4 + (t>>6))*2048 + (size_t)(t&63)*4;
    matvec_acc(gmat, base, e, acc);
    float* op = u_out + (size_t)bid*2048 + (size_t)t*8;
    ((float4*)op)[0] = make_float4(acc[0],acc[1],acc[2],acc[3]);
    ((float4*)op)[1] = make_float4(acc[4],acc[5],acc[6],acc[7]);

    float dv[8] = {0,0,0,0,0,0,0,0};
    matvec_acc(dmat, base, acc, dv);
    __syncthreads();   // guard: laggards may still read XR/XI from inv stage-2
    fwd_store(XR, XI, dv, t, n, h, spec);
}

// ---- final: inv-W-FFT -> u' -> gelu(u'+bias) -> out --------------------
__global__ __launch_bounds__(256) void final_kernel(
    const float2* __restrict__ spec, const float* __restrict__ u_in,
    const unsigned* __restrict__ gmat, const float* __restrict__ bias,
    float* __restrict__ out)
{
    __shared__ f32x4 XR[256], XI[256];
    int t = threadIdx.x, bid = blockIdx.x;
    int n = bid >> 8, h = bid & 255;
    float gu[8];
    inv_fft_to_gu(spec, XR, XI, t, n, h, gu);

    const float* up = u_in + (size_t)bid*2048 + (size_t)t*8;
    float4 ua = ((const float4*)up)[0], ub = ((const float4*)up)[1];
    float uv[8] = {ua.x,ua.y,ua.z,ua.w, ub.x,ub.y,ub.z,ub.w};
    float e[8], acc[8];
#pragma unroll
    for (int c = 0; c < 8; ++c){ e[c] = gu[c] - uv[c]; acc[c] = 2.0f*uv[c]; }
    size_t base = (size_t)(bid*4 + (t>>6))*2048 + (size_t)(t&63)*4;
    matvec_acc(gmat, base, e, acc);
#pragma unroll
    for (int k = 0; k < 8; ++k) acc[k] = gelu_f(acc[k] + bias[k]);
    float* op = out + (size_t)bid*2048 + (size_t)t*8;
    ((float4*)op)[0] = make_float4(acc[0],acc[1],acc[2],acc[3]);
    ((float4*)op)[1] = make_float4(acc[4],acc[5],acc[6],acc[7]);
}

extern "C" void kernel_launch(void* const* d_in, const int* in_sizes, int n_in,
                              void* d_out, int out_size, void* d_ws, size_t ws_size,
                              hipStream_t stream) {
    const float* u_in = (const float*)d_in[0];
    const float* k_in = (const float*)d_in[1];
    const float* Wp[24];
    for (int i = 0; i < 24; ++i) Wp[i] = (const float*)d_in[2+i];
    const float* bias = (const float*)d_in[26];

    char* base = (char*)d_ws;
    unsigned* gmat  = (unsigned*)(base);                  // 32 MiB (bf16 pairs)
    unsigned* dmat  = (unsigned*)(base + 33554432ull);    // 32 MiB
    unsigned* fpack = (unsigned*)(base + 67108864ull);    // 8.45 MB (bf16 pairs)
    float*    u_ws  = (float*)   (base + 75563008ull);    // 8 MiB
    float2*   spec  = (float2*)  (base + 83951616ull);    // 8.45 MB -> ~92 MB

    prep_kernel<<<1153, 256, 0, stream>>>(k_in,
        Wp[0],Wp[1],Wp[2],Wp[3],Wp[4],Wp[5],
        Wp[6],Wp[7],Wp[8],Wp[9],Wp[10],Wp[11],
        Wp[12],Wp[13],Wp[14],Wp[15],Wp[16],Wp[17],
        Wp[18],Wp[19],Wp[20],Wp[21],Wp[22],Wp[23],
        gmat, dmat, fpack);

    fft_fwd_kernel<<<1024, 256, 0, stream>>>(u_in, dmat, spec);
    for (int it = 0; it < 4; ++it){
        ffth_mult_kernel<<<516, 256, 0, stream>>>(spec, fpack);
        if (it < 3){
            born_step_kernel<<<1024, 256, 0, stream>>>(
                spec, (it == 0) ? u_in : u_ws, u_ws, gmat, dmat);
        } else {
            final_kernel<<<1024, 256, 0, stream>>>(spec, u_ws, gmat, bias, (float*)d_out);
        }
    }
}